// Round 1
// 432.906 us; speedup vs baseline: 1.0778x; 1.0778x over previous
//
#include <hip/hip_runtime.h>

// TGRec fused forward, MI355X (gfx950), all f32.
// R4 structure:
//   k_wf   : W = (w_qs_h @ w_ks_h^T) * 1/sqrt(128)   (256x512, tiny)
//   k_qk   : QK = [src|src_t] @ W                    (replaces qproj+qkproj)
//   k_attn : lane-per-row attention; masked rows skipped entirely;
//            writes att (output 1) + normalized S in-place over QK.
//   k_epi  : unchanged validated epilogue, consuming S.
// S = sum_n softmax_n * k_in[n]  (associativity: V-projection deferred).

__device__ __forceinline__ void fma4(float4& a, float s, const float4& w) {
  a.x = fmaf(s, w.x, a.x); a.y = fmaf(s, w.y, a.y);
  a.z = fmaf(s, w.z, a.z); a.w = fmaf(s, w.w, a.w);
}
__device__ __forceinline__ float dot4(const float4& a, const float4& b) {
  return a.x * b.x + a.y * b.y + a.z * b.z + a.w * b.w;
}

// ---------------------------------------------------------------------------
// K-1: W[c, h*256+j] = (1/sqrt(128)) * sum_d w_qs[c, h*128+d] * w_ks[j, h*128+d]
// 131072 outputs, K=128. Trivial FLOPs; w_ks is L2-resident after first touch.
__global__ __launch_bounds__(256) void k_wf(const float* __restrict__ w_qs,
                                            const float* __restrict__ w_ks,
                                            float* __restrict__ W) {
  const int idx = blockIdx.x * 256 + threadIdx.x;  // 0..131071
  const int c = idx >> 9;                          // 0..255
  const int col = idx & 511;                       // 0..511
  const int h = col >> 8;
  const int j = col & 255;
  const float* a = w_qs + c * 256 + h * 128;
  const float* bk = w_ks + j * 256 + h * 128;
  float acc = 0.f;
#pragma unroll
  for (int d = 0; d < 128; d += 4)
    acc += dot4(*(const float4*)&a[d], *(const float4*)&bk[d]);
  W[idx] = acc * 0.08838834764831845f;  // fold 1/sqrt(128)
}

// ---------------------------------------------------------------------------
// K0: QK = qin @ W   (4096x256 @ 256x512). 16 rows/block, half the cols/block.
// grid 512 -> 2 blocks/CU (8 waves/CU), coalesced W row reads.
__global__ __launch_bounds__(256) void k_qk(const float* __restrict__ src,
                                            const float* __restrict__ srct,
                                            const float* __restrict__ W,
                                            float* __restrict__ QK) {
  __shared__ float sQ[16 * 256];
  const int tid = threadIdx.x;
  const int rb = (blockIdx.x >> 1) * 16;
  const int ch = (blockIdx.x & 1) * 256;
  {
    const int r = tid >> 4;
    const int cb = (tid & 15) * 16;
#pragma unroll
    for (int i = 0; i < 4; ++i) {
      const int c = cb + i * 4;
      float4 v = (c < 128) ? *(const float4*)&src[(rb + r) * 128 + c]
                           : *(const float4*)&srct[(rb + r) * 128 + (c - 128)];
      *(float4*)&sQ[r * 256 + c] = v;
    }
  }
  __syncthreads();
  const int rg = tid >> 6;
  const int cg = tid & 63;
  const int col = ch + cg * 4;
  float4 acc[4] = {};
  for (int k = 0; k < 256; k += 4) {
    const float4 w0 = *(const float4*)&W[(k + 0) * 512 + col];
    const float4 w1 = *(const float4*)&W[(k + 1) * 512 + col];
    const float4 w2 = *(const float4*)&W[(k + 2) * 512 + col];
    const float4 w3 = *(const float4*)&W[(k + 3) * 512 + col];
#pragma unroll
    for (int r = 0; r < 4; ++r) {
      const float4 a = *(const float4*)&sQ[(rg * 4 + r) * 256 + k];
      fma4(acc[r], a.x, w0); fma4(acc[r], a.y, w1);
      fma4(acc[r], a.z, w2); fma4(acc[r], a.w, w3);
    }
  }
#pragma unroll
  for (int r = 0; r < 4; ++r)
    *(float4*)&QK[(rb + rg * 4 + r) * 512 + col] = acc[r];
}

// ---------------------------------------------------------------------------
// K1: attention, lane-per-row. Wave w owns batch b = blockIdx*4+w.
// Pass 1: lane n computes p[n] (qk staged in LDS, broadcast reads); masked
//         lanes issue NO loads. One butterfly per head for the denominator.
// Pass 2: lane owns 4 concat dims; walks ballot-compacted unmasked-row list
//         (rows are L1/L2-hot from pass 1); accumulates normalized S.
__global__ __launch_bounds__(256) void k_attn(const float* __restrict__ seq,
                                              const float* __restrict__ seqt,
                                              const unsigned int* __restrict__ mw,
                                              float* QKS,
                                              float* __restrict__ att) {
  __shared__ float sqk[4][512];
  __shared__ float se0[4][64];
  __shared__ float se1[4][64];
  __shared__ int nlist[4][64];
  const int tid = threadIdx.x;
  const int lane = tid & 63;
  const int w = tid >> 6;
  const int b0 = blockIdx.x * 4;
  const int b = b0 + w;
#pragma unroll
  for (int i = 0; i < 2; ++i) {
    const int f4 = i * 256 + tid;  // 0..511
    const int g = f4 >> 7;
    const int c = (f4 & 127) * 4;
    *(float4*)&sqk[g][c] = *(const float4*)&QKS[(b0 + g) * 512 + c];
  }
  __syncthreads();

  const bool masked = (mw[b * 64 + lane] != 0u);
  const float* srow = seq + b * 8192 + lane * 128;
  const float* trow = seqt + b * 8192 + lane * 128;
  float p0s = 0.f, p0t = 0.f, p1s = 0.f, p1t = 0.f;
  if (!masked) {
#pragma unroll 4
    for (int i = 0; i < 32; ++i) {
      const float4 ks = *(const float4*)&srow[i * 4];
      const float4 kt = *(const float4*)&trow[i * 4];
      const float4 q0s = *(const float4*)&sqk[w][i * 4];
      const float4 q0t = *(const float4*)&sqk[w][128 + i * 4];
      const float4 q1s = *(const float4*)&sqk[w][256 + i * 4];
      const float4 q1t = *(const float4*)&sqk[w][384 + i * 4];
      p0s += dot4(ks, q0s); p0t += dot4(kt, q0t);
      p1s += dot4(ks, q1s); p1t += dot4(kt, q1t);
    }
  }
  // scale already folded into W via k_wf
  const float e0 = masked ? 0.f : __expf(p0s + p0t);
  const float e1 = masked ? 0.f : __expf(p1s + p1t);
  float l0 = e0, l1 = e1;
#pragma unroll
  for (int off = 32; off >= 1; off >>= 1) {
    l0 += __shfl_xor(l0, off);
    l1 += __shfl_xor(l1, off);
  }
  const float a0 = e0 / l0;
  const float a1 = e1 / l1;
  att[b * 64 + lane] = a0;                 // lane n owns att position n
  att[4096 * 64 + b * 64 + lane] = a1;

  const unsigned long long bits = __ballot(!masked);
  const int cnt = __popcll(bits);
  const int pos = __popcll(bits & ((1ull << lane) - 1ull));
  if (!masked) nlist[w][pos] = lane;
  se0[w][lane] = a0;
  se1[w][lane] = a1;
  __syncthreads();

  // Pass 2: lane owns concat dims [4*lane, 4*lane+4)
  const float* kin = (lane < 32) ? (seq + b * 8192 + lane * 4)
                                 : (seqt + b * 8192 + (lane - 32) * 4);
  float4 s0 = {0.f, 0.f, 0.f, 0.f}, s1 = {0.f, 0.f, 0.f, 0.f};
  int t = 0;
  for (; t + 4 <= cnt; t += 4) {  // 4 loads in flight
    const int n0 = nlist[w][t + 0];
    const int n1 = nlist[w][t + 1];
    const int n2 = nlist[w][t + 2];
    const int n3 = nlist[w][t + 3];
    const float4 k0 = *(const float4*)(kin + n0 * 128);
    const float4 k1 = *(const float4*)(kin + n1 * 128);
    const float4 k2 = *(const float4*)(kin + n2 * 128);
    const float4 k3 = *(const float4*)(kin + n3 * 128);
    fma4(s0, se0[w][n0], k0); fma4(s1, se1[w][n0], k0);
    fma4(s0, se0[w][n1], k1); fma4(s1, se1[w][n1], k1);
    fma4(s0, se0[w][n2], k2); fma4(s1, se1[w][n2], k2);
    fma4(s0, se0[w][n3], k3); fma4(s1, se1[w][n3], k3);
  }
  for (; t < cnt; ++t) {
    const int n = nlist[w][t];
    const float4 kv = *(const float4*)(kin + n * 128);
    fma4(s0, se0[w][n], kv);
    fma4(s1, se1[w][n], kv);
  }
  *(float4*)(QKS + b * 512 + lane * 4) = s0;
  *(float4*)(QKS + b * 512 + 256 + lane * 4) = s1;
}

// ---------------------------------------------------------------------------
// K2: epilogue — unchanged validated stages, 4 batches/block, consuming S.
__global__ __launch_bounds__(256) void k_epi(
    const float* __restrict__ S, const float* __restrict__ src,
    const float* __restrict__ srct, const float* __restrict__ w_vs,
    const float* __restrict__ fc_w, const float* __restrict__ fc_b,
    const float* __restrict__ ln_g, const float* __restrict__ ln_b,
    const float* __restrict__ fc1_w, const float* __restrict__ fc1_b,
    const float* __restrict__ fc2_w, const float* __restrict__ fc2_b,
    float* __restrict__ out) {
  __shared__ float sv[4][512];
  __shared__ float qin[4][256];
  __shared__ float ov[4][256];
  __shared__ float xx[4][256];
  __shared__ float hcat[4][384];
  __shared__ float h1[4][128];
  __shared__ float stats[4][2];
  const int tid = threadIdx.x;
  const int b0 = blockIdx.x * 4;

  // load S rows: 4 x 512 floats
#pragma unroll
  for (int i = 0; i < 2; ++i) {
    const int f4 = i * 256 + tid;      // 0..511
    const int g = f4 >> 7;
    const int c = (f4 & 127) * 4;
    *(float4*)&sv[g][c] = *(const float4*)&S[(b0 + g) * 512 + c];
  }
  // load q_in = [src | src_t]: 4 x 256 floats
  {
    const int g = tid >> 6;
    const int c = (tid & 63) * 4;
    float4 v = (c < 128) ? *(const float4*)&src[(b0 + g) * 128 + c]
                         : *(const float4*)&srct[(b0 + g) * 128 + (c - 128)];
    *(float4*)&qin[g][c] = v;
  }
  __syncthreads();

  // ov[g][j] = sum_t sv[g][h*256+t] * w_vs[t, j],  h = j>>7
  {
    const int h = tid >> 7;
    float acc[4] = {0.f, 0.f, 0.f, 0.f};
    for (int t = 0; t < 256; ++t) {
      const float w = w_vs[t * 256 + tid];
#pragma unroll
      for (int g = 0; g < 4; ++g) acc[g] = fmaf(sv[g][h * 256 + t], w, acc[g]);
    }
#pragma unroll
    for (int g = 0; g < 4; ++g) ov[g][tid] = acc[g];
  }
  __syncthreads();

  // xx[g][j] = ov[g] @ fc_w[:,j] + fc_b[j] + qin[g][j]
  {
    float acc[4] = {0.f, 0.f, 0.f, 0.f};
    for (int d = 0; d < 256; ++d) {
      const float w = fc_w[d * 256 + tid];
#pragma unroll
      for (int g = 0; g < 4; ++g) acc[g] = fmaf(ov[g][d], w, acc[g]);
    }
    const float fb = fc_b[tid];
#pragma unroll
    for (int g = 0; g < 4; ++g) xx[g][tid] = acc[g] + fb + qin[g][tid];
  }
  __syncthreads();

  // LayerNorm stats (serial per row, exact)
  if (tid < 4) {
    const int g = tid;
    float s = 0.f, ss = 0.f;
    for (int j = 0; j < 256; ++j) {
      const float x = xx[g][j];
      s += x; ss += x * x;
    }
    const float mu = s * (1.0f / 256.0f);
    const float var = ss * (1.0f / 256.0f) - mu * mu;
    stats[g][0] = mu;
    stats[g][1] = rsqrtf(var + 1e-5f);
  }
  __syncthreads();
  {
    const float gg = ln_g[tid], bb = ln_b[tid];
#pragma unroll
    for (int g = 0; g < 4; ++g)
      hcat[g][tid] = (xx[g][tid] - stats[g][0]) * stats[g][1] * gg + bb;
  }
#pragma unroll
  for (int i = 0; i < 2; ++i) {
    const int idx = i * 256 + tid;     // 0..511
    const int g = idx >> 7, c = idx & 127;
    hcat[g][256 + c] = src[(b0 + g) * 128 + c];
  }
  __syncthreads();

  // fc1 + relu: col = tid&127, two g per thread
  {
    const int col = tid & 127;
    const int gp = (tid >> 7) * 2;
    float acc0 = fc1_b[col], acc1 = acc0;
    for (int d = 0; d < 384; ++d) {
      const float w = fc1_w[d * 128 + col];
      acc0 = fmaf(hcat[gp][d], w, acc0);
      acc1 = fmaf(hcat[gp + 1][d], w, acc1);
    }
    h1[gp][col] = fmaxf(acc0, 0.f);
    h1[gp + 1][col] = fmaxf(acc1, 0.f);
  }
  __syncthreads();

  // fc2 -> merged
  {
    const int col = tid & 127;
    const int gp = (tid >> 7) * 2;
    float acc0 = fc2_b[col], acc1 = acc0;
    for (int d = 0; d < 128; ++d) {
      const float w = fc2_w[d * 128 + col];
      acc0 = fmaf(h1[gp][d], w, acc0);
      acc1 = fmaf(h1[gp + 1][d], w, acc1);
    }
    out[(b0 + gp) * 128 + col] = acc0;
    out[(b0 + gp + 1) * 128 + col] = acc1;
  }
}

// ---------------------------------------------------------------------------
extern "C" void kernel_launch(void* const* d_in, const int* in_sizes, int n_in,
                              void* d_out, int out_size, void* d_ws,
                              size_t ws_size, hipStream_t stream) {
  (void)in_sizes; (void)n_in; (void)out_size; (void)ws_size;
  const float* src = (const float*)d_in[0];
  const float* srct = (const float*)d_in[1];
  const float* seq = (const float*)d_in[2];
  const float* seqt = (const float*)d_in[3];
  const unsigned int* mask = (const unsigned int*)d_in[4];
  const float* w_qs = (const float*)d_in[5];
  const float* w_ks = (const float*)d_in[6];
  const float* w_vs = (const float*)d_in[7];
  const float* fc_w = (const float*)d_in[8];
  const float* fc_b = (const float*)d_in[9];
  const float* ln_g = (const float*)d_in[10];
  const float* ln_b = (const float*)d_in[11];
  const float* fc1_w = (const float*)d_in[12];
  const float* fc1_b = (const float*)d_in[13];
  const float* fc2_w = (const float*)d_in[14];
  const float* fc2_b = (const float*)d_in[15];
  float* out = (float*)d_out;              // merged: 4096x128
  float* att = out + 4096 * 128;           // attn_sq: 8192x64
  float* W = (float*)d_ws;                 // 256x512 fused qk weight
  float* QKS = W + 256 * 512;              // 4096x512 (qk, then S in-place)
  k_wf<<<512, 256, 0, stream>>>(w_qs, w_ks, W);
  k_qk<<<512, 256, 0, stream>>>(src, srct, W, QKS);
  k_attn<<<1024, 256, 0, stream>>>(seq, seqt, mask, QKS, att);
  k_epi<<<1024, 256, 0, stream>>>(QKS, src, srct, w_vs, fc_w, fc_b, ln_g,
                                  ln_b, fc1_w, fc1_b, fc2_w, fc2_b, out);
}

// Round 2
// 384.526 us; speedup vs baseline: 1.2134x; 1.1258x over previous
//
#include <hip/hip_runtime.h>

// TGRec fused forward, MI355X (gfx950), all f32.
// R5 structure:
//   k_wf   : W = (w_qs_h @ w_ks_h^T) * 1/sqrt(128)   (256x512, tiny)
//   k_qk   : QK = [src|src_t] @ W                    (validated R4)
//   k_attn : 1 batch/block, 4 waves split concat dims; lane=row for scores,
//            cross-wave LDS reduce; lane=dim for S accumulation over the
//            ballot-compacted unmasked list. grid 4096 (was 1024, grid-capped).
//   k_epi  : validated stage structure; LDS reads vectorized to float4,
//            serial LayerNorm replaced with wave-parallel reduction.
// S = sum_n softmax_n * k_in[n]  (associativity: V-projection deferred).

__device__ __forceinline__ void fma4(float4& a, float s, const float4& w) {
  a.x = fmaf(s, w.x, a.x); a.y = fmaf(s, w.y, a.y);
  a.z = fmaf(s, w.z, a.z); a.w = fmaf(s, w.w, a.w);
}
__device__ __forceinline__ float dot4(const float4& a, const float4& b) {
  return a.x * b.x + a.y * b.y + a.z * b.z + a.w * b.w;
}

// ---------------------------------------------------------------------------
// K-1: W[c, h*256+j] = (1/sqrt(128)) * sum_d w_qs[c, h*128+d] * w_ks[j, h*128+d]
__global__ __launch_bounds__(256) void k_wf(const float* __restrict__ w_qs,
                                            const float* __restrict__ w_ks,
                                            float* __restrict__ W) {
  const int idx = blockIdx.x * 256 + threadIdx.x;  // 0..131071
  const int c = idx >> 9;                          // 0..255
  const int col = idx & 511;                       // 0..511
  const int h = col >> 8;
  const int j = col & 255;
  const float* a = w_qs + c * 256 + h * 128;
  const float* bk = w_ks + j * 256 + h * 128;
  float acc = 0.f;
#pragma unroll
  for (int d = 0; d < 128; d += 4)
    acc += dot4(*(const float4*)&a[d], *(const float4*)&bk[d]);
  W[idx] = acc * 0.08838834764831845f;  // fold 1/sqrt(128)
}

// ---------------------------------------------------------------------------
// K0: QK = qin @ W   (4096x256 @ 256x512). [validated R4]
__global__ __launch_bounds__(256) void k_qk(const float* __restrict__ src,
                                            const float* __restrict__ srct,
                                            const float* __restrict__ W,
                                            float* __restrict__ QK) {
  __shared__ float sQ[16 * 256];
  const int tid = threadIdx.x;
  const int rb = (blockIdx.x >> 1) * 16;
  const int ch = (blockIdx.x & 1) * 256;
  {
    const int r = tid >> 4;
    const int cb = (tid & 15) * 16;
#pragma unroll
    for (int i = 0; i < 4; ++i) {
      const int c = cb + i * 4;
      float4 v = (c < 128) ? *(const float4*)&src[(rb + r) * 128 + c]
                           : *(const float4*)&srct[(rb + r) * 128 + (c - 128)];
      *(float4*)&sQ[r * 256 + c] = v;
    }
  }
  __syncthreads();
  const int rg = tid >> 6;
  const int cg = tid & 63;
  const int col = ch + cg * 4;
  float4 acc[4] = {};
  for (int k = 0; k < 256; k += 4) {
    const float4 w0 = *(const float4*)&W[(k + 0) * 512 + col];
    const float4 w1 = *(const float4*)&W[(k + 1) * 512 + col];
    const float4 w2 = *(const float4*)&W[(k + 2) * 512 + col];
    const float4 w3 = *(const float4*)&W[(k + 3) * 512 + col];
#pragma unroll
    for (int r = 0; r < 4; ++r) {
      const float4 a = *(const float4*)&sQ[(rg * 4 + r) * 256 + k];
      fma4(acc[r], a.x, w0); fma4(acc[r], a.y, w1);
      fma4(acc[r], a.z, w2); fma4(acc[r], a.w, w3);
    }
  }
#pragma unroll
  for (int r = 0; r < 4; ++r)
    *(float4*)&QK[(rb + rg * 4 + r) * 512 + col] = acc[r];
}

// ---------------------------------------------------------------------------
// K1: attention, 1 batch/block (grid 4096), 4 waves split the 256 concat dims.
// Pass 1: lane = row; wave w computes partial dot over dims [64w,64w+64);
//         partials reduced across waves via LDS. Masked lanes load nothing.
// Pass 2: lane = scalar dim 64w+lane; walks compacted unmasked list; each
//         wave re-reads exactly its own pass-1 bytes (L1/L2-hot).
__global__ __launch_bounds__(256) void k_attn(const float* __restrict__ seq,
                                              const float* __restrict__ seqt,
                                              const unsigned int* __restrict__ mw,
                                              float* QKS,
                                              float* __restrict__ att) {
  __shared__ float sqk[512];
  __shared__ float part0[4][64];
  __shared__ float part1[4][64];
  __shared__ float sa0[64];
  __shared__ float sa1[64];
  __shared__ int nlist[64];
  const int tid = threadIdx.x;
  const int lane = tid & 63;
  const int w = tid >> 6;
  const int b = blockIdx.x;

  if (tid < 128)
    *(float4*)&sqk[tid * 4] = *(const float4*)&QKS[b * 512 + tid * 4];
  const bool masked = (mw[b * 64 + lane] != 0u);
  __syncthreads();

  // Pass 1: wave w owns concat dims [64w, 64w+64)
  const float* rowp = (w < 2) ? (seq + b * 8192 + lane * 128 + w * 64)
                              : (seqt + b * 8192 + lane * 128 + (w - 2) * 64);
  float p0 = 0.f, p1 = 0.f;
  if (!masked) {
    const float* q0 = &sqk[w * 64];
    const float* q1 = &sqk[256 + w * 64];
#pragma unroll 8
    for (int i = 0; i < 16; ++i) {
      const float4 kv = *(const float4*)&rowp[i * 4];
      p0 += dot4(kv, *(const float4*)&q0[i * 4]);
      p1 += dot4(kv, *(const float4*)&q1[i * 4]);
    }
  }
  part0[w][lane] = p0;
  part1[w][lane] = p1;
  __syncthreads();

  const float fp0 =
      part0[0][lane] + part0[1][lane] + part0[2][lane] + part0[3][lane];
  const float fp1 =
      part1[0][lane] + part1[1][lane] + part1[2][lane] + part1[3][lane];
  const float e0 = masked ? 0.f : __expf(fp0);
  const float e1 = masked ? 0.f : __expf(fp1);
  float l0 = e0, l1 = e1;
#pragma unroll
  for (int off = 32; off >= 1; off >>= 1) {
    l0 += __shfl_xor(l0, off);
    l1 += __shfl_xor(l1, off);
  }
  const float a0 = e0 / l0;
  const float a1 = e1 / l1;
  const unsigned long long bits = __ballot(!masked);
  if (w == 0) {
    att[b * 64 + lane] = a0;
    att[4096 * 64 + b * 64 + lane] = a1;
    sa0[lane] = a0;
    sa1[lane] = a1;
    const int pos = __popcll(bits & ((1ull << lane) - 1ull));
    if (!masked) nlist[pos] = lane;
  }
  __syncthreads();

  // Pass 2: lane owns concat dim 64w+lane (scalar)
  const int cnt = __popcll(bits);
  const float* kin2 = (w < 2) ? (seq + b * 8192 + w * 64 + lane)
                              : (seqt + b * 8192 + (w - 2) * 64 + lane);
  float s0 = 0.f, s1 = 0.f;
  int t = 0;
  for (; t + 4 <= cnt; t += 4) {  // 4 loads in flight
    const int n0 = nlist[t + 0];
    const int n1 = nlist[t + 1];
    const int n2 = nlist[t + 2];
    const int n3 = nlist[t + 3];
    const float k0 = kin2[n0 * 128];
    const float k1 = kin2[n1 * 128];
    const float k2 = kin2[n2 * 128];
    const float k3 = kin2[n3 * 128];
    s0 = fmaf(sa0[n0], k0, s0); s1 = fmaf(sa1[n0], k0, s1);
    s0 = fmaf(sa0[n1], k1, s0); s1 = fmaf(sa1[n1], k1, s1);
    s0 = fmaf(sa0[n2], k2, s0); s1 = fmaf(sa1[n2], k2, s1);
    s0 = fmaf(sa0[n3], k3, s0); s1 = fmaf(sa1[n3], k3, s1);
  }
  for (; t < cnt; ++t) {
    const int n = nlist[t];
    const float kv = kin2[n * 128];
    s0 = fmaf(sa0[n], kv, s0);
    s1 = fmaf(sa1[n], kv, s1);
  }
  QKS[b * 512 + w * 64 + lane] = s0;
  QKS[b * 512 + 256 + w * 64 + lane] = s1;
}

// ---------------------------------------------------------------------------
// K2: epilogue — validated stages, 4 batches/block; float4 LDS reads,
// wave-parallel LayerNorm.
__global__ __launch_bounds__(256) void k_epi(
    const float* __restrict__ S, const float* __restrict__ src,
    const float* __restrict__ srct, const float* __restrict__ w_vs,
    const float* __restrict__ fc_w, const float* __restrict__ fc_b,
    const float* __restrict__ ln_g, const float* __restrict__ ln_b,
    const float* __restrict__ fc1_w, const float* __restrict__ fc1_b,
    const float* __restrict__ fc2_w, const float* __restrict__ fc2_b,
    float* __restrict__ out) {
  __shared__ float sv[4][512];
  __shared__ float qin[4][256];
  __shared__ float ov[4][256];
  __shared__ float hcat[4][384];
  __shared__ float h1[4][128];
  __shared__ float red[4][4][2];  // [wave][g][sum, sumsq]
  const int tid = threadIdx.x;
  const int lane = tid & 63;
  const int wv = tid >> 6;
  const int b0 = blockIdx.x * 4;

  // load S rows: 4 x 512 floats
#pragma unroll
  for (int i = 0; i < 2; ++i) {
    const int f4 = i * 256 + tid;      // 0..511
    const int g = f4 >> 7;
    const int c = (f4 & 127) * 4;
    *(float4*)&sv[g][c] = *(const float4*)&S[(b0 + g) * 512 + c];
  }
  // load q_in = [src | src_t]: 4 x 256 floats
  {
    const int g = tid >> 6;
    const int c = (tid & 63) * 4;
    float4 v = (c < 128) ? *(const float4*)&src[(b0 + g) * 128 + c]
                         : *(const float4*)&srct[(b0 + g) * 128 + (c - 128)];
    *(float4*)&qin[g][c] = v;
  }
  __syncthreads();

  // ov[g][j] = sum_t sv[g][h*256+t] * w_vs[t, j],  h = j>>7
  const int h = tid >> 7;
  {
    float acc[4] = {0.f, 0.f, 0.f, 0.f};
    for (int t = 0; t < 256; t += 4) {
      const float w0 = w_vs[(t + 0) * 256 + tid];
      const float w1 = w_vs[(t + 1) * 256 + tid];
      const float w2 = w_vs[(t + 2) * 256 + tid];
      const float w3 = w_vs[(t + 3) * 256 + tid];
#pragma unroll
      for (int g = 0; g < 4; ++g) {
        const float4 s4 = *(const float4*)&sv[g][h * 256 + t];
        acc[g] = fmaf(s4.x, w0, acc[g]);
        acc[g] = fmaf(s4.y, w1, acc[g]);
        acc[g] = fmaf(s4.z, w2, acc[g]);
        acc[g] = fmaf(s4.w, w3, acc[g]);
      }
    }
#pragma unroll
    for (int g = 0; g < 4; ++g) ov[g][tid] = acc[g];
  }
  __syncthreads();

  // x[g] = ov[g] @ fc_w[:,tid] + fc_b[tid] + qin[g][tid]  (kept in registers)
  float x[4];
  {
    float acc[4] = {0.f, 0.f, 0.f, 0.f};
    for (int d = 0; d < 256; d += 4) {
      const float w0 = fc_w[(d + 0) * 256 + tid];
      const float w1 = fc_w[(d + 1) * 256 + tid];
      const float w2 = fc_w[(d + 2) * 256 + tid];
      const float w3 = fc_w[(d + 3) * 256 + tid];
#pragma unroll
      for (int g = 0; g < 4; ++g) {
        const float4 o4 = *(const float4*)&ov[g][d];
        acc[g] = fmaf(o4.x, w0, acc[g]);
        acc[g] = fmaf(o4.y, w1, acc[g]);
        acc[g] = fmaf(o4.z, w2, acc[g]);
        acc[g] = fmaf(o4.w, w3, acc[g]);
      }
    }
    const float fb = fc_b[tid];
#pragma unroll
    for (int g = 0; g < 4; ++g) x[g] = acc[g] + fb + qin[g][tid];
  }

  // wave-parallel LayerNorm stats
#pragma unroll
  for (int g = 0; g < 4; ++g) {
    float s = x[g];
    float q = x[g] * x[g];
#pragma unroll
    for (int off = 32; off >= 1; off >>= 1) {
      s += __shfl_xor(s, off);
      q += __shfl_xor(q, off);
    }
    if (lane == 0) {
      red[wv][g][0] = s;
      red[wv][g][1] = q;
    }
  }
  __syncthreads();
  {
    const float gg = ln_g[tid], bb = ln_b[tid];
#pragma unroll
    for (int g = 0; g < 4; ++g) {
      const float s = red[0][g][0] + red[1][g][0] + red[2][g][0] + red[3][g][0];
      const float q = red[0][g][1] + red[1][g][1] + red[2][g][1] + red[3][g][1];
      const float mu = s * (1.0f / 256.0f);
      const float rstd = rsqrtf(q * (1.0f / 256.0f) - mu * mu + 1e-5f);
      hcat[g][tid] = (x[g] - mu) * rstd * gg + bb;
    }
  }
  // hcat tail = src row (already staged in qin[g][0..127])
#pragma unroll
  for (int i = 0; i < 2; ++i) {
    const int idx = i * 256 + tid;     // 0..511
    const int g = idx >> 7, c = idx & 127;
    hcat[g][256 + c] = qin[g][c];
  }
  __syncthreads();

  // fc1 + relu: col = tid&127, two g per thread
  {
    const int col = tid & 127;
    const int gp = (tid >> 7) * 2;
    float acc0 = fc1_b[col], acc1 = acc0;
    for (int d = 0; d < 384; d += 4) {
      const float w0 = fc1_w[(d + 0) * 128 + col];
      const float w1 = fc1_w[(d + 1) * 128 + col];
      const float w2 = fc1_w[(d + 2) * 128 + col];
      const float w3 = fc1_w[(d + 3) * 128 + col];
      const float4 a4 = *(const float4*)&hcat[gp][d];
      const float4 b4 = *(const float4*)&hcat[gp + 1][d];
      acc0 = fmaf(a4.x, w0, acc0); acc0 = fmaf(a4.y, w1, acc0);
      acc0 = fmaf(a4.z, w2, acc0); acc0 = fmaf(a4.w, w3, acc0);
      acc1 = fmaf(b4.x, w0, acc1); acc1 = fmaf(b4.y, w1, acc1);
      acc1 = fmaf(b4.z, w2, acc1); acc1 = fmaf(b4.w, w3, acc1);
    }
    h1[gp][col] = fmaxf(acc0, 0.f);
    h1[gp + 1][col] = fmaxf(acc1, 0.f);
  }
  __syncthreads();

  // fc2 -> merged
  {
    const int col = tid & 127;
    const int gp = (tid >> 7) * 2;
    float acc0 = fc2_b[col], acc1 = acc0;
    for (int d = 0; d < 128; d += 4) {
      const float w0 = fc2_w[(d + 0) * 128 + col];
      const float w1 = fc2_w[(d + 1) * 128 + col];
      const float w2 = fc2_w[(d + 2) * 128 + col];
      const float w3 = fc2_w[(d + 3) * 128 + col];
      const float4 a4 = *(const float4*)&h1[gp][d];
      const float4 b4 = *(const float4*)&h1[gp + 1][d];
      acc0 = fmaf(a4.x, w0, acc0); acc0 = fmaf(a4.y, w1, acc0);
      acc0 = fmaf(a4.z, w2, acc0); acc0 = fmaf(a4.w, w3, acc0);
      acc1 = fmaf(b4.x, w0, acc1); acc1 = fmaf(b4.y, w1, acc1);
      acc1 = fmaf(b4.z, w2, acc1); acc1 = fmaf(b4.w, w3, acc1);
    }
    out[(b0 + gp) * 128 + col] = acc0;
    out[(b0 + gp + 1) * 128 + col] = acc1;
  }
}

// ---------------------------------------------------------------------------
extern "C" void kernel_launch(void* const* d_in, const int* in_sizes, int n_in,
                              void* d_out, int out_size, void* d_ws,
                              size_t ws_size, hipStream_t stream) {
  (void)in_sizes; (void)n_in; (void)out_size; (void)ws_size;
  const float* src = (const float*)d_in[0];
  const float* srct = (const float*)d_in[1];
  const float* seq = (const float*)d_in[2];
  const float* seqt = (const float*)d_in[3];
  const unsigned int* mask = (const unsigned int*)d_in[4];
  const float* w_qs = (const float*)d_in[5];
  const float* w_ks = (const float*)d_in[6];
  const float* w_vs = (const float*)d_in[7];
  const float* fc_w = (const float*)d_in[8];
  const float* fc_b = (const float*)d_in[9];
  const float* ln_g = (const float*)d_in[10];
  const float* ln_b = (const float*)d_in[11];
  const float* fc1_w = (const float*)d_in[12];
  const float* fc1_b = (const float*)d_in[13];
  const float* fc2_w = (const float*)d_in[14];
  const float* fc2_b = (const float*)d_in[15];
  float* out = (float*)d_out;              // merged: 4096x128
  float* att = out + 4096 * 128;           // attn_sq: 8192x64
  float* W = (float*)d_ws;                 // 256x512 fused qk weight
  float* QKS = W + 256 * 512;              // 4096x512 (qk, then S in-place)
  k_wf<<<512, 256, 0, stream>>>(w_qs, w_ks, W);
  k_qk<<<512, 256, 0, stream>>>(src, srct, W, QKS);
  k_attn<<<4096, 256, 0, stream>>>(seq, seqt, mask, QKS, att);
  k_epi<<<1024, 256, 0, stream>>>(QKS, src, srct, w_vs, fc_w, fc_b, ln_g,
                                  ln_b, fc1_w, fc1_b, fc2_w, fc2_b, out);
}